// Round 6
// baseline (347.118 us; speedup 1.0000x reference)
//
#include <hip/hip_runtime.h>
#include <math.h>

#define NN 65536        // nodes
#define NE 524288       // edges (without self loops)
#define D 128
#define ED 32
#define NEG_SLOPE 0.2f

typedef short bf16x8 __attribute__((ext_vector_type(8)));
typedef float f32x4 __attribute__((ext_vector_type(4)));
typedef unsigned short ushort_t;

__device__ __forceinline__ float leaky(float x) { return x > 0.f ? x : NEG_SLOPE * x; }
__device__ __forceinline__ float gelu_exact(float x) {
    return 0.5f * x * (1.f + erff(x * 0.70710678118654752440f));
}
__device__ __forceinline__ unsigned short bf16_rne(float x) {
    unsigned u = __float_as_uint(x);
    return (unsigned short)((u + 0x7FFFu + ((u >> 16) & 1u)) >> 16);
}
__device__ __forceinline__ void unpack8(int4 r, float* f) {
    unsigned u0 = (unsigned)r.x, u1 = (unsigned)r.y, u2 = (unsigned)r.z, u3 = (unsigned)r.w;
    f[0] = __uint_as_float(u0 << 16); f[1] = __uint_as_float(u0 & 0xFFFF0000u);
    f[2] = __uint_as_float(u1 << 16); f[3] = __uint_as_float(u1 & 0xFFFF0000u);
    f[4] = __uint_as_float(u2 << 16); f[5] = __uint_as_float(u2 & 0xFFFF0000u);
    f[6] = __uint_as_float(u3 << 16); f[7] = __uint_as_float(u3 & 0xFFFF0000u);
}

// ---------------- k_front: fused {ale (wvec inline) | wpack} — NO atomics ----------------

__global__ __launch_bounds__(256) void k_front(const float* __restrict__ ea,
        const int* __restrict__ srcArr,
        const float* __restrict__ We, const float* __restrict__ ae,
        const float* __restrict__ Ws, short* __restrict__ Whp, short* __restrict__ Wlp,
        int4* __restrict__ edata_eo) {
    if (blockIdx.x >= NE / 256) {
        // ---- wpack role: pack W into MFMA fragment order, split bf16 hi/lo ----
        int t = (blockIdx.x - NE / 256) * 256 + threadIdx.x;
        if (t >= 3 * 4 * 4 * 128) return;
        int n = t & 127;
        int q = (t >> 7) & 3;
        int ks = (t >> 9) & 3;
        int l = t >> 11;
        const float* w = Ws + (size_t)l * D * D;
        size_t obase = (size_t)l * D * D + ((size_t)((ks * 4 + q) * 128) + n) * 8;
        #pragma unroll
        for (int j = 0; j < 8; ++j) {
            float x = w[(size_t)(ks * 32 + q * 8 + j) * D + n];
            unsigned short hb = bf16_rne(x);
            float hf = __uint_as_float(((unsigned)hb) << 16);
            Whp[obase + j] = (short)hb;
            Wlp[obase + j] = (short)bf16_rne(x - hf);
        }
        return;
    }
    // ---- ale role ----
    __shared__ __align__(16) float wv[3 * ED];
    int t = threadIdx.x;
    if (t < 3 * ED) {
        int l = t >> 5, k = t & 31;
        const float4* w = (const float4*)(We + (size_t)(l * ED + k) * D);
        const float4* a = (const float4*)(ae + (size_t)l * D);
        float s = 0.f;
        #pragma unroll
        for (int i = 0; i < D / 4; ++i) {
            float4 x = w[i], y = a[i];
            s += x.x * y.x + x.y * y.y + x.z * y.z + x.w * y.w;
        }
        wv[t] = s;
    }
    __syncthreads();
    int e = blockIdx.x * 256 + t;
    const float4* row = (const float4*)(ea + (size_t)e * ED);
    const float4* w0 = (const float4*)(wv);
    const float4* w1 = (const float4*)(wv + ED);
    const float4* w2 = (const float4*)(wv + 2 * ED);
    float s0 = 0.f, s1 = 0.f, s2 = 0.f;
    #pragma unroll
    for (int i = 0; i < ED / 4; ++i) {
        float4 v = row[i];
        float4 a = w0[i], b = w1[i], c = w2[i];
        s0 += v.x * a.x + v.y * a.y + v.z * a.z + v.w * a.w;
        s1 += v.x * b.x + v.y * b.y + v.z * b.z + v.w * b.w;
        s2 += v.x * c.x + v.y * c.y + v.z * c.z + v.w * c.w;
    }
    edata_eo[e] = make_int4(srcArr[e], __float_as_int(s0), __float_as_int(s1), __float_as_int(s2));
}

// ---------------- shared GEMM body (16 rows/wave, 64 rows/block) ----------------

__device__ __forceinline__ void gemm_body(int b, const float* __restrict__ A,
        const short* __restrict__ Whp, const short* __restrict__ Wlp,
        const float* __restrict__ a_s, const float* __restrict__ a_d,
        ushort_t* __restrict__ Hb, float* __restrict__ als, float* __restrict__ ald) {
    __shared__ int4 Bs[2048];   // 32KB: [0..1023]=hi, [1024..2047]=lo; reused for transpose
    int t = threadIdx.x;
    int wave = t >> 6, lane = t & 63;
    int l16 = lane & 15, q = lane >> 4;
    int rows_base = b * 64 + wave * 16;

    const int4* wh4 = (const int4*)Whp;
    const int4* wl4 = (const int4*)Wlp;
    const short* bsh = (const short*)Bs;
    const short* bsl = (const short*)(Bs + 1024);

    f32x4 acc[8] = {};
    #pragma unroll
    for (int h2 = 0; h2 < 2; ++h2) {
        if (h2) __syncthreads();
        #pragma unroll
        for (int i = 0; i < 4; ++i) {
            Bs[t + 256 * i] = wh4[h2 * 1024 + t + 256 * i];
            Bs[1024 + t + 256 * i] = wl4[h2 * 1024 + t + 256 * i];
        }
        __syncthreads();
        #pragma unroll
        for (int kk = 0; kk < 2; ++kk) {
            int ks = h2 * 2 + kk;
            const float* ap = A + (size_t)(rows_base + l16) * D + ks * 32 + q * 8;
            float4 v0 = *(const float4*)ap;
            float4 v1 = *(const float4*)(ap + 4);
            float f[8] = {v0.x, v0.y, v0.z, v0.w, v1.x, v1.y, v1.z, v1.w};
            bf16x8 ah, alo;
            #pragma unroll
            for (int j = 0; j < 8; ++j) {
                unsigned short hb = bf16_rne(f[j]);
                float hf = __uint_as_float(((unsigned)hb) << 16);
                ah[j]  = (short)hb;
                alo[j] = (short)bf16_rne(f[j] - hf);
            }
            #pragma unroll
            for (int nt = 0; nt < 8; ++nt) {
                int idx = (((kk * 4 + q) * 128) + nt * 16 + l16) * 8;
                bf16x8 bh = *(const bf16x8*)(bsh + idx);
                bf16x8 bl = *(const bf16x8*)(bsl + idx);
                acc[nt] = __builtin_amdgcn_mfma_f32_16x16x32_bf16(bh, ah, acc[nt], 0, 0, 0);
                acc[nt] = __builtin_amdgcn_mfma_f32_16x16x32_bf16(bl, ah, acc[nt], 0, 0, 0);
                acc[nt] = __builtin_amdgcn_mfma_f32_16x16x32_bf16(bh, alo, acc[nt], 0, 0, 0);
            }
        }
    }

    float ps = 0.f, pd = 0.f;
    #pragma unroll
    for (int nt = 0; nt < 8; ++nt) {
        float4 a4 = *(const float4*)(a_s + nt * 16 + q * 4);
        float4 d4 = *(const float4*)(a_d + nt * 16 + q * 4);
        ps += acc[nt][0] * a4.x + acc[nt][1] * a4.y + acc[nt][2] * a4.z + acc[nt][3] * a4.w;
        pd += acc[nt][0] * d4.x + acc[nt][1] * d4.y + acc[nt][2] * d4.z + acc[nt][3] * d4.w;
    }
    ps += __shfl_xor(ps, 16); pd += __shfl_xor(pd, 16);
    ps += __shfl_xor(ps, 32); pd += __shfl_xor(pd, 32);
    if (q == 0) {
        als[rows_base + l16] = ps;
        ald[rows_base + l16] = pd;
    }

    __syncthreads();
    char* tb = (char*)Bs + wave * 4096;
    {
        int row = l16;
        unsigned key = (unsigned)(row & 7) << 4;
        #pragma unroll
        for (int nt = 0; nt < 8; ++nt) {
            ushort4 pk;
            pk.x = bf16_rne(acc[nt][0]);
            pk.y = bf16_rne(acc[nt][1]);
            pk.z = bf16_rne(acc[nt][2]);
            pk.w = bf16_rne(acc[nt][3]);
            unsigned byteoff = (unsigned)row * 256u + (unsigned)(nt * 16 + q * 4) * 2u;
            *(ushort4*)(tb + (byteoff ^ key)) = pk;
        }
    }
    __syncthreads();
    #pragma unroll
    for (int i = 0; i < 4; ++i) {
        int m = lane + 64 * i;
        unsigned row = (unsigned)m >> 4;
        unsigned byteoff = (unsigned)m * 16u;
        unsigned addr = byteoff ^ ((row & 7u) << 4);
        int4 v = *(const int4*)(tb + addr);
        *(int4*)((char*)Hb + (size_t)rows_base * 256 + (size_t)m * 16) = v;
    }
}

// ---------------- k_h1g0: {hi-byte histogram (512 blocks) | layer-0 GEMM (1024 blocks)} ----------------

__global__ __launch_bounds__(256) void k_h1g0(const int* __restrict__ dstArr,
        int* __restrict__ C,
        const float* __restrict__ x, const short* __restrict__ Whp,
        const short* __restrict__ Wlp, const float* __restrict__ a_s,
        const float* __restrict__ a_d, ushort_t* __restrict__ Hb,
        float* __restrict__ als, float* __restrict__ ald) {
    int t = threadIdx.x;
    if (blockIdx.x < 512) {
        __shared__ int hist[256];
        hist[t] = 0;
        __syncthreads();
        int base = blockIdx.x * 1024;
        #pragma unroll
        for (int i = 0; i < 4; ++i) {
            int d = dstArr[base + i * 256 + t];
            atomicAdd(&hist[d >> 8], 1);
        }
        __syncthreads();
        C[blockIdx.x * 256 + t] = hist[t];
        return;
    }
    gemm_body(blockIdx.x - 512, x, Whp, Wlp, a_s, a_d, Hb, als, ald);
}

// ---------------- k_scanA: per-bin exclusive scan over 512 blocks ----------------

__global__ __launch_bounds__(256) void k_scanA(int* __restrict__ C, int* __restrict__ T) {
    __shared__ int s[512];
    int t = threadIdx.x, h = blockIdx.x;
    int a0 = C[t * 256 + h];
    int a1 = C[(t + 256) * 256 + h];
    s[t] = a0; s[t + 256] = a1;
    __syncthreads();
    for (int off = 1; off < 512; off <<= 1) {
        int v0 = (t >= off) ? s[t - off] : 0;
        int v1 = (t + 256 >= off) ? s[t + 256 - off] : 0;
        __syncthreads();
        s[t] += v0; s[t + 256] += v1;
        __syncthreads();
    }
    C[t * 256 + h] = s[t] - a0;
    C[(t + 256) * 256 + h] = s[t + 256] - a1;
    if (t == 255) T[h] = s[511];
}

// ---------------- k_scanB: exclusive scan of 256 bucket totals -> H ----------------

__global__ __launch_bounds__(256) void k_scanB(const int* __restrict__ T, int* __restrict__ H,
                                               int* __restrict__ rp) {
    __shared__ int s[256];
    int t = threadIdx.x;
    int v = T[t];
    s[t] = v;
    __syncthreads();
    for (int off = 1; off < 256; off <<= 1) {
        int x = (t >= off) ? s[t - off] : 0;
        __syncthreads();
        s[t] += x;
        __syncthreads();
    }
    H[t] = s[t] - v;
    if (t == 255) { H[256] = s[255]; rp[NN] = s[255]; }
}

// ---------------- k_rank1: partition edge records into hi-buckets (LDS atomics only) ----------------

__global__ __launch_bounds__(256) void k_rank1(const int* __restrict__ dstArr,
        const int4* __restrict__ edata_eo, const int* __restrict__ C,
        const int* __restrict__ H, int4* __restrict__ eordR, int* __restrict__ eordD) {
    __shared__ int base[256];
    __shared__ int cnt[256];
    int t = threadIdx.x, b = blockIdx.x;
    base[t] = C[b * 256 + t] + H[t];
    cnt[t] = 0;
    __syncthreads();
    #pragma unroll
    for (int i = 0; i < 4; ++i) {
        int e = b * 1024 + i * 256 + t;
        int d = dstArr[e];
        int4 rec = edata_eo[e];
        int hi = d >> 8;
        int r = atomicAdd(&cnt[hi], 1);
        int p = base[hi] + r;
        eordR[p] = rec;
        eordD[p] = d;
    }
}

// ---------------- k_rank2: within hi-bucket, sort by lo-byte -> CSR edata + rp ----------------

__global__ __launch_bounds__(256) void k_rank2(const int* __restrict__ eordD,
        const int4* __restrict__ eordR, const int* __restrict__ H,
        int4* __restrict__ edata, int* __restrict__ rp) {
    __shared__ int h2[256];
    __shared__ int sc[256];
    __shared__ int cnt[256];
    int t = threadIdx.x, h = blockIdx.x;
    int s0 = H[h], s1 = H[h + 1];
    h2[t] = 0; cnt[t] = 0;
    __syncthreads();
    for (int i = s0 + t; i < s1; i += 256) atomicAdd(&h2[eordD[i] & 255], 1);
    __syncthreads();
    int v = h2[t];
    sc[t] = v;
    __syncthreads();
    for (int off = 1; off < 256; off <<= 1) {
        int x = (t >= off) ? sc[t - off] : 0;
        __syncthreads();
        sc[t] += x;
        __syncthreads();
    }
    int baseLo = sc[t] - v;            // exclusive prefix
    rp[h * 256 + t] = s0 + baseLo;
    __syncthreads();
    sc[t] = baseLo;
    __syncthreads();
    for (int i = s0 + t; i < s1; i += 256) {
        int d = eordD[i];
        int4 rec = eordR[i];
        int lo = d & 255;
        int r = atomicAdd(&cnt[lo], 1);
        edata[s0 + sc[lo] + r] = rec;
    }
}

// ---------------- k_gemm: standalone GEMM for layers 1,2 ----------------

__global__ __launch_bounds__(256) void k_gemm(const float* __restrict__ A,
        const short* __restrict__ Whp, const short* __restrict__ Wlp,
        const float* __restrict__ a_s, const float* __restrict__ a_d,
        ushort_t* __restrict__ Hb, float* __restrict__ als, float* __restrict__ ald) {
    gemm_body(blockIdx.x, A, Whp, Wlp, a_s, a_d, Hb, als, ald);
}

// ---------------- k_aggr: fused softmax + gather, early-issue row loads ----------------

__global__ __launch_bounds__(256) void k_aggr(const ushort_t* __restrict__ hb,
        const float* __restrict__ als, const float* __restrict__ ald,
        const int4* __restrict__ edata, const int* __restrict__ rp,
        const float* __restrict__ bias, int lsel, float* __restrict__ out_f32) {
    int t = threadIdx.x;
    int lane = t & 63;
    int l16 = lane & 15;
    int qb = lane & 48;                 // quarter base within wave
    int n = blockIdx.x * 16 + (t >> 4); // one node per 16 threads
    int s = rp[n], e = rp[n + 1];
    int deg = e - s;
    float aldd = ald[n];
    float alsn = als[n];
    float inv_deg = (deg > 0) ? 1.f / (float)deg : 0.f;

    int4 hvp = *(const int4*)(hb + (size_t)n * D + l16 * 8);
    float acc8[8];

    if (deg <= 16) {
        // -- load edge record + src attention (critical-path head) --
        int sn0 = 0;
        float alev0 = 0.f, alsg = 0.f;
        if (l16 < deg) {
            int4 ed = edata[s + l16];
            sn0 = ed.x;
            alev0 = __int_as_float((lsel == 0) ? ed.y : ((lsel == 1) ? ed.z : ed.w));
            alsg = als[sn0];
        }

        // -- broadcast src ids and ISSUE all row gathers now --
        int sA[8], sB[8];
        #pragma unroll
        for (int i = 0; i < 8; ++i) { sA[i] = __shfl(sn0, qb + i); sB[i] = __shfl(sn0, qb + 8 + i); }
        int4 rb[8];
        #pragma unroll
        for (int i = 0; i < 8; ++i) rb[i] = *(const int4*)(hb + (size_t)sA[i] * D + l16 * 8);
        bool more = (deg > 8);
        int4 rb2[8];
        if (more) {
            #pragma unroll
            for (int i = 0; i < 8; ++i) rb2[i] = *(const int4*)(hb + (size_t)sB[i] * D + l16 * 8);
        }

        // -- softmax reduction runs while gathers are in flight --
        float al0 = (l16 < deg) ? leaky(alsg + aldd + alev0) : -1e30f;
        float mm = al0, asum = alev0;
        #pragma unroll
        for (int off = 1; off < 16; off <<= 1) {
            mm = fmaxf(mm, __shfl_xor(mm, off));
            asum += __shfl_xor(asum, off);
        }
        float self_al = leaky(alsn + aldd + asum * inv_deg);
        mm = fmaxf(mm, self_al);
        float p0 = (l16 < deg) ? __expf(al0 - mm) : 0.f;
        float den = p0;
        #pragma unroll
        for (int off = 1; off < 16; off <<= 1) den += __shfl_xor(den, off);
        float es = __expf(self_al - mm);
        den += es;
        float inv = 1.f / den;
        float w0 = p0 * inv;       // exactly 0 for l16 >= deg
        float wself = es * inv;

        float fv[8];
        unpack8(hvp, fv);
        #pragma unroll
        for (int j = 0; j < 8; ++j) acc8[j] = wself * fv[j];

        float wA[8], wB[8];
        #pragma unroll
        for (int i = 0; i < 8; ++i) { wA[i] = __shfl(w0, qb + i); wB[i] = __shfl(w0, qb + 8 + i); }

        #pragma unroll
        for (int i = 0; i < 8; ++i) {
            float f[8];
            unpack8(rb[i], f);
            #pragma unroll
            for (int j = 0; j < 8; ++j) acc8[j] += wA[i] * f[j];
        }
        if (more) {
            #pragma unroll
            for (int i = 0; i < 8; ++i) {
                float f[8];
                unpack8(rb2[i], f);
                #pragma unroll
                for (int j = 0; j < 8; ++j) acc8[j] += wB[i] * f[j];
            }
        }
    } else {
        // general path (rare): chunked 3-pass with recompute
        float mm = -1e30f, asum = 0.f;
        for (int base = s; base < e; base += 16) {
            int j = base + l16;
            if (j < e) {
                int4 ed = edata[j];
                float alev = __int_as_float((lsel == 0) ? ed.y : ((lsel == 1) ? ed.z : ed.w));
                asum += alev;
                mm = fmaxf(mm, leaky(als[ed.x] + aldd + alev));
            }
        }
        #pragma unroll
        for (int off = 1; off < 16; off <<= 1) {
            mm = fmaxf(mm, __shfl_xor(mm, off));
            asum += __shfl_xor(asum, off);
        }
        float self_al = leaky(alsn + aldd + asum * inv_deg);
        mm = fmaxf(mm, self_al);
        float den = 0.f;
        for (int base = s; base < e; base += 16) {
            int j = base + l16;
            if (j < e) {
                int4 ed = edata[j];
                float alev = __int_as_float((lsel == 0) ? ed.y : ((lsel == 1) ? ed.z : ed.w));
                den += __expf(leaky(als[ed.x] + aldd + alev) - mm);
            }
        }
        #pragma unroll
        for (int off = 1; off < 16; off <<= 1) den += __shfl_xor(den, off);
        float es = __expf(self_al - mm);
        den += es;
        float inv = 1.f / den;
        float wself = es * inv;
        float fv[8];
        unpack8(hvp, fv);
        #pragma unroll
        for (int j = 0; j < 8; ++j) acc8[j] = wself * fv[j];
        for (int base = s; base < e; base += 16) {
            int cnt = min(e - base, 16);
            int sn = 0;
            float w = 0.f;
            if (l16 < cnt) {
                int4 ed = edata[base + l16];
                sn = ed.x;
                float alev = __int_as_float((lsel == 0) ? ed.y : ((lsel == 1) ? ed.z : ed.w));
                w = __expf(leaky(als[sn] + aldd + alev) - mm) * inv;
            }
            for (int tt = 0; tt < cnt; ++tt) {
                int st = __shfl(sn, qb + tt);
                float wt = __shfl(w, qb + tt);
                int4 r = *(const int4*)(hb + (size_t)st * D + l16 * 8);
                float f[8];
                unpack8(r, f);
                #pragma unroll
                for (int j = 0; j < 8; ++j) acc8[j] += wt * f[j];
            }
        }
    }

    const float4* b4 = (const float4*)(bias + l16 * 8);
    float4 b0 = b4[0], b1 = b4[1];
    float bb[8] = {b0.x, b0.y, b0.z, b0.w, b1.x, b1.y, b1.z, b1.w};
    float o[8];
    #pragma unroll
    for (int j = 0; j < 8; ++j) o[j] = gelu_exact(acc8[j] + bb[j]);

    float4* o4 = (float4*)(out_f32 + (size_t)n * D + l16 * 8);
    o4[0] = make_float4(o[0], o[1], o[2], o[3]);
    o4[1] = make_float4(o[4], o[5], o[6], o[7]);
}

// ---------------- launch ----------------

extern "C" void kernel_launch(void* const* d_in, const int* in_sizes, int n_in,
                              void* d_out, int out_size, void* d_ws, size_t ws_size,
                              hipStream_t stream) {
    (void)in_sizes; (void)n_in; (void)out_size; (void)ws_size;
    const float* x        = (const float*)d_in[0];
    const int*   eidx     = (const int*)d_in[1];   // [2, NE]: row0=src, row1=dst
    const float* ea       = (const float*)d_in[2];
    const float* Ws       = (const float*)d_in[3];
    const float* att_src  = (const float*)d_in[4];
    const float* att_dst  = (const float*)d_in[5];
    const float* W_edge   = (const float*)d_in[6];
    const float* att_edge = (const float*)d_in[7];
    const float* bias     = (const float*)d_in[8];
    float* out = (float*)d_out;

    char* ws = (char*)d_ws;
    size_t off = 0;
    auto alloc = [&](size_t bytes) {
        void* p = ws + off;
        off += (bytes + 255) & ~(size_t)255;
        return p;
    };
    ushort_t* Hb   = (ushort_t*)alloc((size_t)NN * D * 2);  // bf16 h after GEMM (gather input)
    float*    Hx   = (float*)alloc((size_t)NN * D * 4);     // fp32 activations between layers
    float*    als  = (float*)alloc((size_t)NN * 4);
    float*    ald  = (float*)alloc((size_t)NN * 4);
    int4*     edata= (int4*)alloc((size_t)(NE + 16) * 16);  // CSR-order (src, ale0, ale1, ale2)
    int4*     edata_eo = (int4*)alloc((size_t)NE * 16);     // edge-order records
    int4*     eordR = (int4*)alloc((size_t)NE * 16);        // hi-bucket-partitioned records
    int*      eordD = (int*)alloc((size_t)NE * 4);          // hi-bucket-partitioned dst
    int*      C    = (int*)alloc((size_t)512 * 256 * 4);    // per-(block,hi-bin) counts
    int*      T    = (int*)alloc(256 * 4);                  // per-bucket totals
    int*      H    = (int*)alloc(260 * 4);                  // bucket bases (excl scan)
    int*      rp   = (int*)alloc((size_t)(NN + 4) * 4);
    short*    Whp  = (short*)alloc((size_t)3 * D * D * 2);
    short*    Wlp  = (short*)alloc((size_t)3 * D * D * 2);

    const int* e_src = eidx;
    const int* e_dst = eidx + NE;

    // front: ale + wpack (no atomics)
    k_front<<<NE / 256 + 24, 256, 0, stream>>>(ea, e_src, W_edge, att_edge,
                                               Ws, Whp, Wlp, edata_eo);
    // hi-byte histogram || layer-0 GEMM
    k_h1g0<<<512 + NN / 64, 256, 0, stream>>>(e_dst, C, x, Whp, Wlp, att_src, att_dst,
                                              Hb, als, ald);
    // scans + two-level counting-sort CSR build (LDS atomics only)
    k_scanA<<<256, 256, 0, stream>>>(C, T);
    k_scanB<<<256 / 256, 256, 0, stream>>>(T, H, rp);
    k_rank1<<<512, 256, 0, stream>>>(e_dst, edata_eo, C, H, eordR, eordD);
    k_rank2<<<256, 256, 0, stream>>>(eordD, eordR, H, edata, rp);

    // layers: aggr(l) -> gemm(l+1), final aggr writes out
    for (int l = 0; l < 3; ++l) {
        bool last = (l == 2);
        k_aggr<<<NN / 16, 256, 0, stream>>>(Hb, als, ald, edata, rp, bias + (size_t)l * D, l,
                                            last ? out : Hx);
        if (!last) {
            k_gemm<<<NN / 64, 256, 0, stream>>>(Hx, Whp + (size_t)(l + 1) * D * D,
                                                Wlp + (size_t)(l + 1) * D * D,
                                                att_src + (size_t)(l + 1) * D,
                                                att_dst + (size_t)(l + 1) * D,
                                                Hb, als, ald);
        }
    }
}